// Round 2
// baseline (349.082 us; speedup 1.0000x reference)
//
#include <hip/hip_runtime.h>

// Spiking NN collapses to 3 dependent masked binary matvecs (input drive is
// nonzero only at t=0; decaying membranes can never re-cross threshold):
//   enc = (u < x);  s0 = (W0*M0)@enc > 1;  s1 = (W1*M1)@s0 > 1;
//   out = ((W2*M2)@s1 > 1) ? 1/time_steps : 0
// HBM-bound: 384 MB streamed once (floor ~56 us at 6.9 TB/s achievable).
// R1: one wave/row = 16 waves/CU was latency-limited (~half BW). Now 2 waves
// per row (8192 waves, 8 blocks/CU) + 4 independent f64 acc chains to double
// in-flight loads. f64 acc keeps the >1.0 spike compare bit-stable vs numpy.

constexpr int N = 4096;
constexpr int HALF = N / 2;                 // columns per wave
constexpr int ITERS = HALF / 4 / 64;        // 8 float4 iters per wave

template <bool ENCODE, bool FINAL>
__global__ __launch_bounds__(256) void snn_layer(
    const float* __restrict__ W, const float* __restrict__ M,
    const float* __restrict__ S, const float* __restrict__ U,
    const int* __restrict__ t_steps, float* __restrict__ out)
{
    const int lane = threadIdx.x & 63;
    const int wave = threadIdx.x >> 6;      // 0..3
    const int rsub = wave >> 1;             // row within block (0..1)
    const int half = wave & 1;              // which half of the row
    const int row  = (blockIdx.x << 1) | rsub;

    const size_t base = (size_t)row * N + (size_t)half * HALF;
    const float4* W4 = reinterpret_cast<const float4*>(W + base);
    const float4* M4 = reinterpret_cast<const float4*>(M + base);
    const float4* S4 = reinterpret_cast<const float4*>(S + half * HALF);
    const float4* U4 = reinterpret_cast<const float4*>(U + (ENCODE ? half * HALF : 0));

    double a0 = 0.0, a1 = 0.0, a2 = 0.0, a3 = 0.0;   // 4 independent chains
#pragma unroll
    for (int it = 0; it < ITERS; ++it) {
        const int idx = it * 64 + lane;              // coalesced 1 KB/wave/instr
        float4 w = W4[idx];
        float4 m = M4[idx];
        float4 s = S4[idx];
        if (ENCODE) {
            float4 uu = U4[idx];
            s.x = (uu.x < s.x) ? 1.0f : 0.0f;
            s.y = (uu.y < s.y) ? 1.0f : 0.0f;
            s.z = (uu.z < s.z) ? 1.0f : 0.0f;
            s.w = (uu.w < s.w) ? 1.0f : 0.0f;
        }
        // m,s are exact {0,1}; w*(m*s) is exact in f64 -> near-exact partial sum
        a0 = fma((double)w.x, (double)(m.x * s.x), a0);
        a1 = fma((double)w.y, (double)(m.y * s.y), a1);
        a2 = fma((double)w.z, (double)(m.z * s.z), a2);
        a3 = fma((double)w.w, (double)(m.w * s.w), a3);
    }
    double acc = (a0 + a1) + (a2 + a3);

#pragma unroll
    for (int off = 32; off > 0; off >>= 1)
        acc += __shfl_down(acc, off, 64);

    __shared__ double part[4];
    if (lane == 0) part[wave] = acc;
    __syncthreads();

    if (threadIdx.x < 2) {                  // thread t -> row (blockIdx*2 + t)
        const double tot = part[threadIdx.x * 2] + part[threadIdx.x * 2 + 1];
        const int r = (blockIdx.x << 1) | threadIdx.x;
        if (FINAL) {
            const float scale = 1.0f / (float)t_steps[0];
            out[r] = (tot > 1.0) ? scale : 0.0f;
        } else {
            out[r] = (tot > 1.0) ? 1.0f : 0.0f;
        }
    }
}

extern "C" void kernel_launch(void* const* d_in, const int* in_sizes, int n_in,
                              void* d_out, int out_size, void* d_ws, size_t ws_size,
                              hipStream_t stream)
{
    const float* x  = (const float*)d_in[0];
    const float* u  = (const float*)d_in[1];
    const float* W0 = (const float*)d_in[2];
    const float* W1 = (const float*)d_in[3];
    const float* W2 = (const float*)d_in[4];
    const float* M0 = (const float*)d_in[5];
    const float* M1 = (const float*)d_in[6];
    const float* M2 = (const float*)d_in[7];
    const int* t_steps = (const int*)d_in[8];
    float* out = (float*)d_out;

    float* s0 = (float*)d_ws;       // 4096 floats, fully rewritten each call
    float* s1 = s0 + N;             // 4096 floats

    dim3 grid(N / 2), block(256);   // 2 rows/block, 2 waves/row
    snn_layer<true,  false><<<grid, block, 0, stream>>>(W0, M0, x,  u,       nullptr, s0);
    snn_layer<false, false><<<grid, block, 0, stream>>>(W1, M1, s0, nullptr, nullptr, s1);
    snn_layer<false, true ><<<grid, block, 0, stream>>>(W2, M2, s1, nullptr, t_steps, out);
}